// Round 24
// baseline (838.206 us; speedup 1.0000x reference)
//
#include <hip/hip_runtime.h>
#include <math.h>

// Problem constants (static from setup_inputs):
// ll_* : (2,3,256,256) f32;  ws=32, pad=0, E=64
// windows: 128 total (2 imgs x 8x8), 1024 tokens/window, 64 "channels"/token
// Raw-reshape semantics: per-window (1024,64) Q/K matrix row i = flat window
// NCHW buffer chunk [i*64, i*64+64)  (ch = i>>4, pos = (i&15)*64 + c).
// Out matrix row i maps back to window spatial pos p=i; final 1x1 conv mixes
// the 64 "channels" (= columns of O) into 3 output channels + residual.
#define NWIN 128

// ---------------------------------------------------------------------------
// Kernel 1: gate path.  gate = sigmoid(conv1x1(relu(conv3x3(k_vi)),gw2)+gb2)
// k_vi recomputed on the fly from ll_vi (pointwise conv = 3 fma) so plain
// NCHW k_vi never hits HBM.  Output per-window-spatial: Gw[win][pos].
// Block = 16x16 output tile; 64 k_vi channels in 4 chunks of 16.
// ---------------------------------------------------------------------------
__global__ __launch_bounds__(256) void gate_kernel(
    const float* __restrict__ ll_vi,
    const float* __restrict__ pwv, const float* __restrict__ pbv,
    const float* __restrict__ gw1, const float* __restrict__ gb1,
    const float* __restrict__ gw2, const float* __restrict__ gb2,
    float* __restrict__ Gw) {
  __shared__ float lv[3][18][18];     // ll_vi tile + halo
  __shared__ float kv[16][18][18];    // k_vi channel-chunk tile + halo
  __shared__ float w1[9216];          // gw1 staged (16*64*9)

  int b   = blockIdx.z;
  int ty0 = blockIdx.y * 16;
  int tx0 = blockIdx.x * 16;
  int tid = threadIdx.x;
  int tyL = tid >> 4, txL = tid & 15;

  for (int i = tid; i < 9216; i += 256) w1[i] = gw1[i];
  for (int i = tid; i < 3 * 324; i += 256) {
    int k = i / 324, pp = i % 324;
    int yy = pp / 18, xx = pp % 18;
    int gy = ty0 + yy - 1, gx = tx0 + xx - 1;
    float v = 0.f;
    if (gy >= 0 && gy < 256 && gx >= 0 && gx < 256)
      v = ll_vi[(b * 3 + k) * 65536 + gy * 256 + gx];
    lv[k][yy][xx] = v;
  }

  float acc[16];
#pragma unroll
  for (int e = 0; e < 16; e++) acc[e] = gb1[e];

  for (int cc = 0; cc < 4; cc++) {
    __syncthreads();  // covers lv/w1 staging (cc=0) and prior-chunk kv reads
    for (int i = tid; i < 16 * 324; i += 256) {
      int cl = i / 324, pp = i % 324;
      int yy = pp / 18, xx = pp % 18;
      int c = cc * 16 + cl;
      int gy = ty0 + yy - 1, gx = tx0 + xx - 1;
      float v = 0.f;
      if (gy >= 0 && gy < 256 && gx >= 0 && gx < 256)
        v = pbv[c] + pwv[c * 3 + 0] * lv[0][yy][xx]
                   + pwv[c * 3 + 1] * lv[1][yy][xx]
                   + pwv[c * 3 + 2] * lv[2][yy][xx];
      kv[cl][yy][xx] = v;   // zero-pad of the 3x3 conv at image border
    }
    __syncthreads();
    for (int cl = 0; cl < 16; cl++) {
      float kr[3][3];
#pragma unroll
      for (int ky = 0; ky < 3; ky++)
#pragma unroll
        for (int kx = 0; kx < 3; kx++)
          kr[ky][kx] = kv[cl][tyL + ky][txL + kx];
      int c = cc * 16 + cl;
#pragma unroll
      for (int e = 0; e < 16; e++) {        // acc[] stays static-indexed
        const float* wp = &w1[(e * 64 + c) * 9];
        acc[e] += wp[0] * kr[0][0] + wp[1] * kr[0][1] + wp[2] * kr[0][2]
                + wp[3] * kr[1][0] + wp[4] * kr[1][1] + wp[5] * kr[1][2]
                + wp[6] * kr[2][0] + wp[7] * kr[2][1] + wp[8] * kr[2][2];
      }
    }
  }

  float g2 = gb2[0];
#pragma unroll
  for (int e = 0; e < 16; e++) g2 += gw2[e] * fmaxf(acc[e], 0.f);
  float gate = 1.f / (1.f + expf(-g2));

  int gy = ty0 + tyL, gx = tx0 + txL;
  int win = b * 64 + (gy >> 5) * 8 + (gx >> 5);
  int p = (gy & 31) * 32 + (gx & 31);
  Gw[win * 1024 + p] = gate;
}

// ---------------------------------------------------------------------------
// Kernel 2: fully fused — pointwise convs + flash attention + output 1x1 conv
// + residual, per (window, 64-row i-block).
// Q/K tiles built on the fly from the window's 3-ch 32x32 input patches (LDS).
// S[i,j] = (Q_i . K_j) * gate[j]; online softmax over j; O = P @ K;
// epilogue: out[b,:,pix(i)] = ow @ O[i,:] + ob + ll_ir (residual from LDS).
// 256 threads = 16x16, each owns a 4x4 register tile of the 64x64 sub-block.
// LDS: ir 12K + vi 12K + Qs 17.4K + Ksr 16.6K + Ps 17.4K ~= 76KB -> 2 blk/CU.
// ---------------------------------------------------------------------------
__global__ __launch_bounds__(256) void attn_fused_kernel(
    const float* __restrict__ ll_ir, const float* __restrict__ ll_vi,
    const float* __restrict__ pwi, const float* __restrict__ pbi,
    const float* __restrict__ pwv, const float* __restrict__ pbv,
    const float* __restrict__ Gw, const float* __restrict__ ow,
    const float* __restrict__ ob, float* __restrict__ out) {
  __shared__ float ir[3][1024];  // ll_ir window patch (also residual source)
  __shared__ float vi[3][1024];  // ll_vi window patch
  __shared__ float Qs[64][68];   // [c][i_local], pad 68: aligned f4, bc-free
  __shared__ float Ksr[64][65];  // [j_local][c], pad 65: odd stride on cols
  __shared__ float Ps[64][68];   // [i_local][j_local] / epilogue O-tile
  __shared__ float gt[64];

  int win = blockIdx.y;
  int ib  = blockIdx.x;
  int b   = win >> 6;
  int hy  = (win >> 3) & 7;
  int hx  = win & 7;

  int tid = threadIdx.x;
  int ty = tid >> 4, tx = tid & 15;

  // stage both input patches (32-float contiguous rows -> coalesced)
  for (int i = tid; i < 3072; i += 256) {
    int k = i >> 10, pos = i & 1023;
    int y = hy * 32 + (pos >> 5), x = hx * 32 + (pos & 31);
    int gidx = (b * 3 + k) * 65536 + y * 256 + x;
    ir[k][pos] = ll_ir[gidx];
    vi[k][pos] = ll_vi[gidx];
  }
  __syncthreads();

  // build Q i-block: rows ib*64..+63  (ch = ib*4 + (il>>4), pos=(il&15)*64+c)
#pragma unroll
  for (int r = 0; r < 16; r++) {
    int idx = r * 256 + tid;       // 0..4095
    int il = idx >> 6, c = idx & 63;
    int ch = ib * 4 + (il >> 4);
    int pos = (il & 15) * 64 + c;
    Qs[c][il] = pbi[ch] + pwi[ch * 3 + 0] * ir[0][pos]
                        + pwi[ch * 3 + 1] * ir[1][pos]
                        + pwi[ch * 3 + 2] * ir[2][pos];
  }

  float o[4][4] = {};
  float m[4], l[4];
#pragma unroll
  for (int ii = 0; ii < 4; ii++) { m[ii] = -INFINITY; l[ii] = 0.f; }

  for (int jt = 0; jt < 16; jt++) {
    __syncthreads();               // prior PV / Q-build done before overwrite
    // build K j-tile from vi patch (same raw-reshape indexing)
#pragma unroll
    for (int r = 0; r < 16; r++) {
      int idx = r * 256 + tid;
      int jl = idx >> 6, c = idx & 63;
      int ch = jt * 4 + (jl >> 4);
      int pos = (jl & 15) * 64 + c;
      Ksr[jl][c] = pbv[ch] + pwv[ch * 3 + 0] * vi[0][pos]
                           + pwv[ch * 3 + 1] * vi[1][pos]
                           + pwv[ch * 3 + 2] * vi[2][pos];
    }
    if (tid < 64) gt[tid] = Gw[win * 1024 + jt * 64 + tid];
    __syncthreads();

    // ---- E tile (64x64), 4x4 per thread ----
    float e[4][4] = {};
#pragma unroll 8
    for (int c = 0; c < 64; c++) {
      float4 a4 = *(const float4*)&Qs[c][ty * 4];
      float av[4] = {a4.x, a4.y, a4.z, a4.w};
      float bv[4];
#pragma unroll
      for (int jj = 0; jj < 4; jj++) bv[jj] = Ksr[tx * 4 + jj][c];
#pragma unroll
      for (int ii = 0; ii < 4; ii++)
#pragma unroll
        for (int jj = 0; jj < 4; jj++)
          e[ii][jj] = fmaf(av[ii], bv[jj], e[ii][jj]);
    }

    // ---- gate + online softmax (16-lane tx-groups; xor masks 1..8 stay
    //      inside the group on the 64-lane wave) ----
    float gv[4] = {gt[tx * 4], gt[tx * 4 + 1], gt[tx * 4 + 2], gt[tx * 4 + 3]};
    float tmax[4], tsum[4];
#pragma unroll
    for (int ii = 0; ii < 4; ii++) {
#pragma unroll
      for (int jj = 0; jj < 4; jj++) e[ii][jj] *= gv[jj];
      tmax[ii] = fmaxf(fmaxf(e[ii][0], e[ii][1]), fmaxf(e[ii][2], e[ii][3]));
    }
#pragma unroll
    for (int off = 1; off < 16; off <<= 1)
#pragma unroll
      for (int ii = 0; ii < 4; ii++)
        tmax[ii] = fmaxf(tmax[ii], __shfl_xor(tmax[ii], off));

#pragma unroll
    for (int ii = 0; ii < 4; ii++) {
      float mn = fmaxf(m[ii], tmax[ii]);
      float r = expf(m[ii] - mn);   // m=-inf -> 0 on first tile
      m[ii] = mn;
      float s = 0.f;
#pragma unroll
      for (int jj = 0; jj < 4; jj++) {
        float pv = expf(e[ii][jj] - mn);
        e[ii][jj] = pv;
        s += pv;
      }
      tsum[ii] = s;
      l[ii] *= r;
#pragma unroll
      for (int ccx = 0; ccx < 4; ccx++) o[ii][ccx] *= r;
    }
#pragma unroll
    for (int off = 1; off < 16; off <<= 1)
#pragma unroll
      for (int ii = 0; ii < 4; ii++)
        tsum[ii] += __shfl_xor(tsum[ii], off);
#pragma unroll
    for (int ii = 0; ii < 4; ii++) l[ii] += tsum[ii];

#pragma unroll
    for (int ii = 0; ii < 4; ii++)
      *(float4*)&Ps[ty * 4 + ii][tx * 4] =
          make_float4(e[ii][0], e[ii][1], e[ii][2], e[ii][3]);
    __syncthreads();

    // ---- PV: o[i][c] += sum_j P[i][j] * K[j][c]  (V == K) ----
#pragma unroll 4
    for (int j4 = 0; j4 < 16; j4++) {
      float4 pr4[4];
#pragma unroll
      for (int ii = 0; ii < 4; ii++)
        pr4[ii] = *(const float4*)&Ps[ty * 4 + ii][j4 * 4];
#pragma unroll
      for (int js = 0; js < 4; js++) {
        int j = j4 * 4 + js;
        float kvr[4];
#pragma unroll
        for (int ccx = 0; ccx < 4; ccx++) kvr[ccx] = Ksr[j][tx * 4 + ccx];
        float pr[4] = {((const float*)&pr4[0])[js], ((const float*)&pr4[1])[js],
                       ((const float*)&pr4[2])[js], ((const float*)&pr4[3])[js]};
#pragma unroll
        for (int ii = 0; ii < 4; ii++)
#pragma unroll
          for (int ccx = 0; ccx < 4; ccx++)
            o[ii][ccx] = fmaf(pr[ii], kvr[ccx], o[ii][ccx]);
      }
    }
  }

  // ---- epilogue: normalized O-tile -> LDS, then 1x1 conv + residual ----
  __syncthreads();   // last PV reads of Ps done before overwrite
#pragma unroll
  for (int ii = 0; ii < 4; ii++) {
    float inv = 1.f / l[ii];
    *(float4*)&Ps[ty * 4 + ii][tx * 4] =
        make_float4(o[ii][0] * inv, o[ii][1] * inv,
                    o[ii][2] * inv, o[ii][3] * inv);
  }
  __syncthreads();

  if (tid < 64) {
    int p = ib * 64 + tid;          // window spatial pos of out-row i
    const float* Or = &Ps[tid][0];
    float a0 = ob[0], a1 = ob[1], a2 = ob[2];
#pragma unroll 16
    for (int c = 0; c < 64; c++) {
      float v = Or[c];
      a0 = fmaf(ow[c], v, a0);
      a1 = fmaf(ow[64 + c], v, a1);
      a2 = fmaf(ow[128 + c], v, a2);
    }
    int y = hy * 32 + (p >> 5), x = hx * 32 + (p & 31);
    int pix = y * 256 + x;
    out[(b * 3 + 0) * 65536 + pix] = a0 + ir[0][p];
    out[(b * 3 + 1) * 65536 + pix] = a1 + ir[1][p];
    out[(b * 3 + 2) * 65536 + pix] = a2 + ir[2][p];
  }
}

// ---------------------------------------------------------------------------
extern "C" void kernel_launch(void* const* d_in, const int* in_sizes, int n_in,
                              void* d_out, int out_size, void* d_ws, size_t ws_size,
                              hipStream_t stream) {
  const float* ll_ir = (const float*)d_in[0];
  const float* ll_vi = (const float*)d_in[1];
  const float* pw_ir = (const float*)d_in[2];
  const float* pb_ir = (const float*)d_in[3];
  const float* pw_vi = (const float*)d_in[4];
  const float* pb_vi = (const float*)d_in[5];
  const float* gw1   = (const float*)d_in[6];
  const float* gb1   = (const float*)d_in[7];
  const float* gw2   = (const float*)d_in[8];
  const float* gb2   = (const float*)d_in[9];
  const float* ow    = (const float*)d_in[10];
  const float* ob    = (const float*)d_in[11];
  float* out = (float*)d_out;

  // workspace: Gw only — 128*1024 floats = 512 KB
  float* Gw = (float*)d_ws;

  gate_kernel<<<dim3(16, 16, 2), 256, 0, stream>>>(ll_vi, pw_vi, pb_vi,
                                                   gw1, gb1, gw2, gb2, Gw);
  attn_fused_kernel<<<dim3(16, NWIN), 256, 0, stream>>>(
      ll_ir, ll_vi, pw_ir, pb_ir, pw_vi, pb_vi, Gw, ow, ob, out);
}